// Round 1
// baseline (1560.839 us; speedup 1.0000x reference)
//
#include <hip/hip_runtime.h>

#define D 128

// ---------------- K1: degree histogram ----------------
__global__ void k_degrees(const int* __restrict__ src, const int* __restrict__ dst,
                          int* __restrict__ deg_out, int* __restrict__ deg_in, int E) {
    int e = blockIdx.x * blockDim.x + threadIdx.x;
    if (e < E) {
        atomicAdd(&deg_out[src[e]], 1);
        atomicAdd(&deg_in[dst[e]], 1);
    }
}

// ---------------- K2: fold W_conv into W_aggr top half ----------------
// Wcomb[0:128]   = W_conv @ W_aggr[0:128]
// Wcomb[128:256] = W_aggr[128:256]
// beff           = b_aggr + b_conv @ W_aggr[0:128]
__global__ void k_wcomb(const float* __restrict__ Wc, const float* __restrict__ Wa,
                        const float* __restrict__ bc, const float* __restrict__ ba,
                        float* __restrict__ Wcomb, float* __restrict__ beff) {
    int b = blockIdx.x;
    int j = threadIdx.x;  // 128 threads
    if (b < 128) {
        float acc = 0.f;
        for (int k = 0; k < 128; k++) acc += Wc[b * 128 + k] * Wa[k * 128 + j];
        Wcomb[b * 128 + j] = acc;
    } else if (b < 256) {
        Wcomb[b * 128 + j] = Wa[b * 128 + j];
    } else {
        float acc = ba[j];
        for (int k = 0; k < 128; k++) acc += bc[k] * Wa[k * 128 + j];
        beff[j] = acc;
    }
}

// ---------------- K3: edge scatter: y[dst] += x[src] * norm_src[src] ----------------
__global__ __launch_bounds__(256) void k_scatter(const float* __restrict__ x,
                                                 const int* __restrict__ src,
                                                 const int* __restrict__ dst,
                                                 const int* __restrict__ deg_out,
                                                 float* __restrict__ y, int E) {
    long long tid = (long long)blockIdx.x * blockDim.x + threadIdx.x;
    int e = (int)(tid >> 5);
    int lane = (int)(tid & 31);
    if (e >= E) return;
    int s = src[e];
    int d = dst[e];
    float ns = rsqrtf((float)(deg_out[s] > 1 ? deg_out[s] : 1));
    const float4 v = *(const float4*)&x[(size_t)s * D + lane * 4];
    float* yp = &y[(size_t)d * D + lane * 4];
    unsafeAtomicAdd(yp + 0, v.x * ns);
    unsafeAtomicAdd(yp + 1, v.y * ns);
    unsafeAtomicAdd(yp + 2, v.z * ns);
    unsafeAtomicAdd(yp + 3, v.w * ns);
}

// ---------------- K4: fused GEMM: out = [y*norm_dst | x] @ Wcomb + beff ----------------
// block: 256 threads, tile 64 rows x 128 cols, K=256 in 4 chunks of 64
__global__ __launch_bounds__(256) void k_gemm(const float* __restrict__ y,
                                              const float* __restrict__ x,
                                              const int* __restrict__ deg_in,
                                              const float* __restrict__ Wcomb,
                                              const float* __restrict__ beff,
                                              float* __restrict__ out, int N) {
    __shared__ float Ws[64][128];  // 32 KB
    __shared__ float Xs[64][64];   // 16 KB
    __shared__ float nd[64];

    int t = threadIdx.x;
    int row0 = blockIdx.x * 64;
    int cg = t & 31;   // column group: cols cg*4 .. cg*4+3
    int rg = t >> 5;   // row group: rows rg*8 .. rg*8+7

    float acc[8][4];
#pragma unroll
    for (int r = 0; r < 8; r++)
#pragma unroll
        for (int c = 0; c < 4; c++) acc[r][c] = 0.f;

    if (t < 64) {
        int r = row0 + t;
        int dg = (r < N) ? deg_in[r] : 1;
        nd[t] = rsqrtf((float)(dg > 1 ? dg : 1));
    }
    __syncthreads();

    for (int kc = 0; kc < 4; kc++) {
        int kbase = kc * 64;
        // stage W chunk: 64 x 128 floats = 2048 float4 / 256 threads = 8 each
#pragma unroll
        for (int i = 0; i < 8; i++) {
            int idx = t + i * 256;       // float4 index 0..2047
            int rr = idx >> 5;           // 32 float4 per row
            int cc = (idx & 31) * 4;
            *(float4*)&Ws[rr][cc] = *(const float4*)&Wcomb[(size_t)(kbase + rr) * 128 + cc];
        }
        // stage X chunk: 64 rows x 64 k = 1024 float4 / 256 threads = 4 each
#pragma unroll
        for (int i = 0; i < 4; i++) {
            int idx = t + i * 256;       // float4 index 0..1023
            int rr = idx >> 4;           // 16 float4 per row
            int cc = (idx & 15) * 4;
            int r = row0 + rr;
            float4 v = make_float4(0.f, 0.f, 0.f, 0.f);
            if (r < N) {
                if (kc < 2) {
                    v = *(const float4*)&y[(size_t)r * 128 + kbase + cc];
                    float s = nd[rr];
                    v.x *= s; v.y *= s; v.z *= s; v.w *= s;
                } else {
                    v = *(const float4*)&x[(size_t)r * 128 + (kbase - 128) + cc];
                }
            }
            *(float4*)&Xs[rr][cc] = v;
        }
        __syncthreads();

#pragma unroll 8
        for (int kk = 0; kk < 64; kk++) {
            float4 w = *(float4*)&Ws[kk][cg * 4];
#pragma unroll
            for (int r = 0; r < 8; r++) {
                float xv = Xs[rg * 8 + r][kk];
                acc[r][0] += xv * w.x;
                acc[r][1] += xv * w.y;
                acc[r][2] += xv * w.z;
                acc[r][3] += xv * w.w;
            }
        }
        __syncthreads();
    }

    float4 bv = *(const float4*)&beff[cg * 4];
#pragma unroll
    for (int r = 0; r < 8; r++) {
        int rr = row0 + rg * 8 + r;
        if (rr < N) {
            float4 o;
            o.x = acc[r][0] + bv.x;
            o.y = acc[r][1] + bv.y;
            o.z = acc[r][2] + bv.z;
            o.w = acc[r][3] + bv.w;
            *(float4*)&out[(size_t)rr * 128 + cg * 4] = o;
        }
    }
}

extern "C" void kernel_launch(void* const* d_in, const int* in_sizes, int n_in,
                              void* d_out, int out_size, void* d_ws, size_t ws_size,
                              hipStream_t stream) {
    const float* x     = (const float*)d_in[0];
    const int*   src   = (const int*)d_in[1];
    const int*   dst   = (const int*)d_in[2];
    const float* Wconv = (const float*)d_in[3];
    const float* bconv = (const float*)d_in[4];
    const float* Waggr = (const float*)d_in[5];
    const float* baggr = (const float*)d_in[6];
    float* out = (float*)d_out;

    int N = in_sizes[0] / D;
    int E = in_sizes[1];

    char* p = (char*)d_ws;
    float* y = (float*)p;        p += (size_t)N * D * sizeof(float);
    int* deg_out = (int*)p;      p += (size_t)N * sizeof(int);
    int* deg_in  = (int*)p;      p += (size_t)N * sizeof(int);
    float* Wcomb = (float*)p;    p += 256 * 128 * sizeof(float);
    float* beff  = (float*)p;    p += 128 * sizeof(float);

    // zero y + degree arrays (contiguous at start of ws)
    hipMemsetAsync(d_ws, 0, (size_t)N * D * sizeof(float) + (size_t)N * 2 * sizeof(int), stream);

    k_degrees<<<(E + 255) / 256, 256, 0, stream>>>(src, dst, deg_out, deg_in, E);
    k_wcomb<<<257, 128, 0, stream>>>(Wconv, Waggr, bconv, baggr, Wcomb, beff);

    long long scatter_threads = (long long)E * 32;
    int scatter_blocks = (int)((scatter_threads + 255) / 256);
    k_scatter<<<scatter_blocks, 256, 0, stream>>>(x, src, dst, deg_out, y, E);

    k_gemm<<<(N + 63) / 64, 256, 0, stream>>>(y, x, deg_in, Wcomb, beff, out, N);
}

// Round 2
// 399.423 us; speedup vs baseline: 3.9077x; 3.9077x over previous
//
#include <hip/hip_runtime.h>

#define D 128

// ---------------- K1: degree histogram ----------------
__global__ void k_degrees(const int* __restrict__ src, const int* __restrict__ dst,
                          int* __restrict__ deg_out, int* __restrict__ deg_in, int E) {
    int e = blockIdx.x * blockDim.x + threadIdx.x;
    if (e < E) {
        atomicAdd(&deg_out[src[e]], 1);
        atomicAdd(&deg_in[dst[e]], 1);
    }
}

// ---------------- K2: norms from degrees ----------------
__global__ void k_norms(const int* __restrict__ deg_out, const int* __restrict__ deg_in,
                        float* __restrict__ norm_out, float* __restrict__ norm_in, int N) {
    int n = blockIdx.x * blockDim.x + threadIdx.x;
    if (n < N) {
        int a = deg_out[n]; if (a < 1) a = 1;
        int b = deg_in[n];  if (b < 1) b = 1;
        norm_out[n] = rsqrtf((float)a);
        norm_in[n]  = rsqrtf((float)b);
    }
}

// ---------------- K3: exclusive scan of deg_in -> offsets (single block) ----------------
__global__ __launch_bounds__(1024) void k_scan(const int* __restrict__ deg,
                                               int* __restrict__ offsets, int N) {
    __shared__ int sums[1024];
    int t = threadIdx.x;
    int chunk = (N + 1023) >> 10;
    int lo = t * chunk;
    int hi = lo + chunk; if (hi > N) hi = N; if (lo > N) lo = N;
    int s = 0;
    for (int i = lo; i < hi; i++) s += deg[i];
    sums[t] = s;
    __syncthreads();
    for (int off = 1; off < 1024; off <<= 1) {
        int v = (t >= off) ? sums[t - off] : 0;
        __syncthreads();
        sums[t] += v;
        __syncthreads();
    }
    int excl = sums[t] - s;
    for (int i = lo; i < hi; i++) { offsets[i] = excl; excl += deg[i]; }
    if (t == 1023) offsets[N] = sums[1023];
}

// ---------------- K4: bucket fill: edge list sorted by dst ----------------
__global__ void k_bucket(const int* __restrict__ src, const int* __restrict__ dst,
                         const int* __restrict__ offsets, int* __restrict__ cursor,
                         int* __restrict__ edge_src, int E) {
    int e = blockIdx.x * blockDim.x + threadIdx.x;
    if (e < E) {
        int d = dst[e];
        int pos = atomicAdd(&cursor[d], 1);
        edge_src[offsets[d] + pos] = src[e];
    }
}

// ---------------- K5: CSR aggregation: y[n] = norm_in[n] * sum_{s in in(n)} x[s]*norm_out[s]
// one wave (64 lanes) per node, float2 per lane covers D=128
__global__ __launch_bounds__(256) void k_aggr(const float* __restrict__ x,
                                              const int* __restrict__ edge_src,
                                              const int* __restrict__ offsets,
                                              const float* __restrict__ norm_out,
                                              const float* __restrict__ norm_in,
                                              float* __restrict__ y, int N) {
    int node = blockIdx.x * 4 + (threadIdx.x >> 6);
    int lane = threadIdx.x & 63;
    if (node >= N) return;
    int beg = offsets[node];
    int end = offsets[node + 1];
    float2 acc = make_float2(0.f, 0.f);
#pragma unroll 2
    for (int j = beg; j < end; j++) {
        int s = edge_src[j];               // wave-uniform -> s_load
        float ns = norm_out[s];            // wave-uniform -> s_load
        float2 v = *(const float2*)&x[(size_t)s * D + lane * 2];
        acc.x += v.x * ns;
        acc.y += v.y * ns;
    }
    float nd = norm_in[node];
    acc.x *= nd; acc.y *= nd;
    *(float2*)&y[(size_t)node * D + lane * 2] = acc;
}

// ---------------- K6: fold W_conv into W_aggr top half ----------------
__global__ void k_wcomb(const float* __restrict__ Wc, const float* __restrict__ Wa,
                        const float* __restrict__ bc, const float* __restrict__ ba,
                        float* __restrict__ Wcomb, float* __restrict__ beff) {
    int b = blockIdx.x;
    int j = threadIdx.x;  // 128 threads
    if (b < 128) {
        float acc = 0.f;
        for (int k = 0; k < 128; k++) acc += Wc[b * 128 + k] * Wa[k * 128 + j];
        Wcomb[b * 128 + j] = acc;
    } else if (b < 256) {
        Wcomb[b * 128 + j] = Wa[b * 128 + j];
    } else {
        float acc = ba[j];
        for (int k = 0; k < 128; k++) acc += bc[k] * Wa[k * 128 + j];
        beff[j] = acc;
    }
}

// ---------------- K7: fused GEMM: out = [y | x] @ Wcomb + beff ----------------
// (y already carries both norms) block: 256 threads, tile 64 rows x 128 cols
__global__ __launch_bounds__(256) void k_gemm(const float* __restrict__ y,
                                              const float* __restrict__ x,
                                              const float* __restrict__ Wcomb,
                                              const float* __restrict__ beff,
                                              float* __restrict__ out, int N) {
    __shared__ float Ws[64][128];  // 32 KB
    __shared__ float Xs[64][64];   // 16 KB

    int t = threadIdx.x;
    int row0 = blockIdx.x * 64;
    int cg = t & 31;   // column group: cols cg*4 .. cg*4+3
    int rg = t >> 5;   // row group: rows rg*8 .. rg*8+7

    float acc[8][4];
#pragma unroll
    for (int r = 0; r < 8; r++)
#pragma unroll
        for (int c = 0; c < 4; c++) acc[r][c] = 0.f;

    for (int kc = 0; kc < 4; kc++) {
        int kbase = kc * 64;
#pragma unroll
        for (int i = 0; i < 8; i++) {
            int idx = t + i * 256;
            int rr = idx >> 5;
            int cc = (idx & 31) * 4;
            *(float4*)&Ws[rr][cc] = *(const float4*)&Wcomb[(size_t)(kbase + rr) * 128 + cc];
        }
#pragma unroll
        for (int i = 0; i < 4; i++) {
            int idx = t + i * 256;
            int rr = idx >> 4;
            int cc = (idx & 15) * 4;
            int r = row0 + rr;
            float4 v = make_float4(0.f, 0.f, 0.f, 0.f);
            if (r < N) {
                if (kc < 2) v = *(const float4*)&y[(size_t)r * 128 + kbase + cc];
                else        v = *(const float4*)&x[(size_t)r * 128 + (kbase - 128) + cc];
            }
            *(float4*)&Xs[rr][cc] = v;
        }
        __syncthreads();

#pragma unroll 8
        for (int kk = 0; kk < 64; kk++) {
            float4 w = *(float4*)&Ws[kk][cg * 4];
#pragma unroll
            for (int r = 0; r < 8; r++) {
                float xv = Xs[rg * 8 + r][kk];
                acc[r][0] += xv * w.x;
                acc[r][1] += xv * w.y;
                acc[r][2] += xv * w.z;
                acc[r][3] += xv * w.w;
            }
        }
        __syncthreads();
    }

    float4 bv = *(const float4*)&beff[cg * 4];
#pragma unroll
    for (int r = 0; r < 8; r++) {
        int rr = row0 + rg * 8 + r;
        if (rr < N) {
            float4 o;
            o.x = acc[r][0] + bv.x;
            o.y = acc[r][1] + bv.y;
            o.z = acc[r][2] + bv.z;
            o.w = acc[r][3] + bv.w;
            *(float4*)&out[(size_t)rr * 128 + cg * 4] = o;
        }
    }
}

extern "C" void kernel_launch(void* const* d_in, const int* in_sizes, int n_in,
                              void* d_out, int out_size, void* d_ws, size_t ws_size,
                              hipStream_t stream) {
    const float* x     = (const float*)d_in[0];
    const int*   src   = (const int*)d_in[1];
    const int*   dst   = (const int*)d_in[2];
    const float* Wconv = (const float*)d_in[3];
    const float* bconv = (const float*)d_in[4];
    const float* Waggr = (const float*)d_in[5];
    const float* baggr = (const float*)d_in[6];
    float* out = (float*)d_out;

    int N = in_sizes[0] / D;
    int E = in_sizes[1];

    char* p = (char*)d_ws;
    int* deg_out  = (int*)p;   p += (size_t)N * sizeof(int);       // zeroed
    int* deg_in   = (int*)p;   p += (size_t)N * sizeof(int);       // zeroed
    int* cursor   = (int*)p;   p += (size_t)N * sizeof(int);       // zeroed
    int* offsets  = (int*)p;   p += (size_t)(N + 1) * sizeof(int);
    float* norm_out = (float*)p; p += (size_t)N * sizeof(float);
    float* norm_in  = (float*)p; p += (size_t)N * sizeof(float);
    int* edge_src = (int*)p;   p += (size_t)E * sizeof(int);
    float* y      = (float*)p; p += (size_t)N * D * sizeof(float);
    float* Wcomb  = (float*)p; p += 256 * 128 * sizeof(float);
    float* beff   = (float*)p; p += 128 * sizeof(float);

    hipMemsetAsync(d_ws, 0, (size_t)N * 3 * sizeof(int), stream);

    k_degrees<<<(E + 255) / 256, 256, 0, stream>>>(src, dst, deg_out, deg_in, E);
    k_norms<<<(N + 255) / 256, 256, 0, stream>>>(deg_out, deg_in, norm_out, norm_in, N);
    k_scan<<<1, 1024, 0, stream>>>(deg_in, offsets, N);
    k_bucket<<<(E + 255) / 256, 256, 0, stream>>>(src, dst, offsets, cursor, edge_src, E);
    k_aggr<<<(N + 3) / 4, 256, 0, stream>>>(x, edge_src, offsets, norm_out, norm_in, y, N);
    k_wcomb<<<257, 128, 0, stream>>>(Wconv, Waggr, bconv, baggr, Wcomb, beff);
    k_gemm<<<(N + 63) / 64, 256, 0, stream>>>(y, x, Wcomb, beff, out, N);
}

// Round 3
// 292.773 us; speedup vs baseline: 5.3312x; 1.3643x over previous
//
#include <hip/hip_runtime.h>

#define D 128

typedef short short8 __attribute__((ext_vector_type(8)));
typedef float f32x4 __attribute__((ext_vector_type(4)));

static __device__ __forceinline__ unsigned short f2bf(float f) {
    unsigned int u = __float_as_uint(f);
    unsigned int r = (u + 0x7FFFu + ((u >> 16) & 1u)) >> 16;
    return (unsigned short)r;
}
static __device__ __forceinline__ float bf2f(unsigned short h) {
    return __uint_as_float(((unsigned int)h) << 16);
}

// ---------------- K1: degree histogram ----------------
__global__ void k_degrees(const int* __restrict__ src, const int* __restrict__ dst,
                          int* __restrict__ deg_out, int* __restrict__ deg_in, int E) {
    int e = blockIdx.x * blockDim.x + threadIdx.x;
    if (e < E) {
        atomicAdd(&deg_out[src[e]], 1);
        atomicAdd(&deg_in[dst[e]], 1);
    }
}

// ---------------- K2: norms from degrees ----------------
__global__ void k_norms(const int* __restrict__ deg_out, const int* __restrict__ deg_in,
                        float* __restrict__ norm_out, float* __restrict__ norm_in, int N) {
    int n = blockIdx.x * blockDim.x + threadIdx.x;
    if (n < N) {
        int a = deg_out[n]; if (a < 1) a = 1;
        int b = deg_in[n];  if (b < 1) b = 1;
        norm_out[n] = rsqrtf((float)a);
        norm_in[n]  = rsqrtf((float)b);
    }
}

// ---------------- scan (3-phase): deg_in -> exclusive offsets ----------------
__global__ __launch_bounds__(256) void k_scan1(const int* __restrict__ deg,
                                               int* __restrict__ partial, int N) {
    __shared__ int red[256];
    int t = threadIdx.x;
    int base = blockIdx.x * 1024 + t * 4;
    int s = 0;
    if (base + 3 < N) { int4 v = *(const int4*)&deg[base]; s = v.x + v.y + v.z + v.w; }
    else { for (int i = 0; i < 4; i++) if (base + i < N) s += deg[base + i]; }
    red[t] = s; __syncthreads();
    for (int off = 128; off > 0; off >>= 1) {
        if (t < off) red[t] += red[t + off];
        __syncthreads();
    }
    if (t == 0) partial[blockIdx.x] = red[0];
}

__global__ void k_scan2(int* __restrict__ partial, int* __restrict__ offsets, int nb, int N) {
    if (threadIdx.x == 0) {
        int run = 0;
        for (int i = 0; i < nb; i++) { int v = partial[i]; partial[i] = run; run += v; }
        offsets[N] = run;
    }
}

__global__ __launch_bounds__(256) void k_scan3(const int* __restrict__ deg,
                                               const int* __restrict__ partial,
                                               int* __restrict__ offsets, int N) {
    __shared__ int red[256];
    int t = threadIdx.x;
    int base = blockIdx.x * 1024 + t * 4;
    int v[4]; int s = 0;
    for (int i = 0; i < 4; i++) { v[i] = (base + i < N) ? deg[base + i] : 0; s += v[i]; }
    red[t] = s; __syncthreads();
    for (int off = 1; off < 256; off <<= 1) {
        int a = (t >= off) ? red[t - off] : 0;
        __syncthreads();
        red[t] += a;
        __syncthreads();
    }
    int excl = red[t] - s + partial[blockIdx.x];
    for (int i = 0; i < 4; i++) { if (base + i < N) offsets[base + i] = excl; excl += v[i]; }
}

// ---------------- bucket fill: edge srcs grouped by dst ----------------
__global__ void k_bucket(const int* __restrict__ src, const int* __restrict__ dst,
                         const int* __restrict__ offsets, int* __restrict__ cursor,
                         int* __restrict__ edge_src, int E) {
    int e = blockIdx.x * blockDim.x + threadIdx.x;
    if (e < E) {
        int d = dst[e];
        int pos = atomicAdd(&cursor[d], 1);
        edge_src[offsets[d] + pos] = src[e];
    }
}

// ---------------- x -> bf16 ----------------
__global__ __launch_bounds__(256) void k_x2bf(const float* __restrict__ x,
                                              unsigned short* __restrict__ xh, long long total4) {
    long long i = (long long)blockIdx.x * blockDim.x + threadIdx.x;
    if (i < total4) {
        float4 v = *(const float4*)&x[i * 4];
        ushort4 o;
        o.x = f2bf(v.x); o.y = f2bf(v.y); o.z = f2bf(v.z); o.w = f2bf(v.w);
        *(ushort4*)&xh[i * 4] = o;
    }
}

// ---------------- CSR aggregation: yh[n] = bf16(norm_in[n] * sum x[s]*norm_out[s]) ----------------
__global__ __launch_bounds__(256) void k_aggr(const unsigned short* __restrict__ xh,
                                              const int* __restrict__ edge_src,
                                              const int* __restrict__ offsets,
                                              const float* __restrict__ norm_out,
                                              const float* __restrict__ norm_in,
                                              unsigned short* __restrict__ yh, int N) {
    int node = blockIdx.x * 4 + (threadIdx.x >> 6);
    int lane = threadIdx.x & 63;
    if (node >= N) return;
    int beg = offsets[node];
    int end = offsets[node + 1];
    float ax = 0.f, ay = 0.f;
#pragma unroll 2
    for (int j = beg; j < end; j++) {
        int s = edge_src[j];
        float ns = norm_out[s];
        ushort2 v = *(const ushort2*)&xh[(size_t)s * D + lane * 2];
        ax += bf2f(v.x) * ns;
        ay += bf2f(v.y) * ns;
    }
    float nd = norm_in[node];
    ushort2 o;
    o.x = f2bf(ax * nd);
    o.y = f2bf(ay * nd);
    *(ushort2*)&yh[(size_t)node * D + lane * 2] = o;
}

// ---------------- fold W_conv into W_aggr; write bf16 transposed Wt[n][k] ----------------
// Wt[n][k] for k<128: (W_conv @ Wa_top)[k][n]; k>=128: Wa[k][n]. beff fp32.
__global__ void k_wcomb(const float* __restrict__ Wc, const float* __restrict__ Wa,
                        const float* __restrict__ bc, const float* __restrict__ ba,
                        unsigned short* __restrict__ Wt, float* __restrict__ beff) {
    int b = blockIdx.x;   // k index 0..255, or 256 for bias
    int j = threadIdx.x;  // n index, 128 threads
    if (b < 128) {
        float acc = 0.f;
        for (int k = 0; k < 128; k++) acc += Wc[b * 128 + k] * Wa[k * 128 + j];
        Wt[(size_t)j * 256 + b] = f2bf(acc);
    } else if (b < 256) {
        Wt[(size_t)j * 256 + b] = f2bf(Wa[b * 128 + j]);
    } else {
        float acc = ba[j];
        for (int k = 0; k < 128; k++) acc += bc[k] * Wa[k * 128 + j];
        beff[j] = acc;
    }
}

// ---------------- MFMA GEMM: out = [yh | xh] @ W + beff ----------------
// block: 256 threads (4 waves), tile 64 rows x 128 cols, K=256 in 2 halves of 128
#define WT_STRIDE 136  // bf16 elems per LDS row (pad 256->136 per half): 2-way bank alias only
__global__ __launch_bounds__(256) void k_gemm(const unsigned short* __restrict__ yh,
                                              const unsigned short* __restrict__ xh,
                                              const unsigned short* __restrict__ Wt,
                                              const float* __restrict__ beff,
                                              float* __restrict__ out, int N) {
    __shared__ unsigned short Bs[128 * WT_STRIDE];  // 34.8 KB

    int t = threadIdx.x;
    int w = t >> 6;        // wave 0..3
    int lane = t & 63;
    int m = lane & 15;     // row-in-tile for A, col for C/D
    int q = lane >> 4;     // quad 0..3
    int row0 = blockIdx.x * 64;
    int arow = row0 + w * 16 + m;
    bool arow_ok = arow < N;

    f32x4 acc[8];
#pragma unroll
    for (int ct = 0; ct < 8; ct++) acc[ct] = (f32x4){0.f, 0.f, 0.f, 0.f};

    for (int kh = 0; kh < 2; kh++) {
        // stage Wt[:, kh*128 .. +128] into LDS: 128 rows x 128 bf16 (256B/row)
#pragma unroll
        for (int i = 0; i < 8; i++) {
            int idx = t + i * 256;        // 0..2047 uint4 units
            int rr = idx >> 4;            // 16 uint4 per row
            int cc = (idx & 15) * 8;      // bf16 offset
            *(short8*)&Bs[rr * WT_STRIDE + cc] =
                *(const short8*)&Wt[(size_t)rr * 256 + kh * 128 + cc];
        }
        __syncthreads();

        const unsigned short* Abase = (kh == 0) ? yh : xh;
        const unsigned short* arowp = Abase + (size_t)arow * D;

#pragma unroll
        for (int kk = 0; kk < 4; kk++) {
            short8 a = (short8){0,0,0,0,0,0,0,0};
            if (arow_ok) a = *(const short8*)&arowp[kk * 32 + q * 8];
#pragma unroll
            for (int ct = 0; ct < 8; ct++) {
                short8 b = *(const short8*)&Bs[(ct * 16 + m) * WT_STRIDE + kk * 32 + q * 8];
                acc[ct] = __builtin_amdgcn_mfma_f32_16x16x32_bf16(a, b, acc[ct], 0, 0, 0);
            }
        }
        __syncthreads();
    }

    // epilogue: C layout col=lane&15(m), row=q*4+j
#pragma unroll
    for (int ct = 0; ct < 8; ct++) {
        int col = ct * 16 + m;
        float bv = beff[col];
#pragma unroll
        for (int j = 0; j < 4; j++) {
            int r = row0 + w * 16 + q * 4 + j;
            if (r < N) out[(size_t)r * D + col] = acc[ct][j] + bv;
        }
    }
}

extern "C" void kernel_launch(void* const* d_in, const int* in_sizes, int n_in,
                              void* d_out, int out_size, void* d_ws, size_t ws_size,
                              hipStream_t stream) {
    const float* x     = (const float*)d_in[0];
    const int*   src   = (const int*)d_in[1];
    const int*   dst   = (const int*)d_in[2];
    const float* Wconv = (const float*)d_in[3];
    const float* bconv = (const float*)d_in[4];
    const float* Waggr = (const float*)d_in[5];
    const float* baggr = (const float*)d_in[6];
    float* out = (float*)d_out;

    int N = in_sizes[0] / D;
    int E = in_sizes[1];
    int nscan = (N + 1023) / 1024;

    char* p = (char*)d_ws;
    int* deg_out  = (int*)p;   p += (size_t)N * sizeof(int);       // zeroed
    int* deg_in   = (int*)p;   p += (size_t)N * sizeof(int);       // zeroed
    int* cursor   = (int*)p;   p += (size_t)N * sizeof(int);       // zeroed
    int* offsets  = (int*)p;   p += (size_t)(N + 1) * sizeof(int);
    int* partial  = (int*)p;   p += (size_t)(nscan + 1) * sizeof(int);
    float* norm_out = (float*)p; p += (size_t)N * sizeof(float);
    float* norm_in  = (float*)p; p += (size_t)N * sizeof(float);
    float* beff   = (float*)p; p += 128 * sizeof(float);
    int* edge_src = (int*)p;   p += (size_t)E * sizeof(int);
    unsigned short* xh = (unsigned short*)p; p += (size_t)N * D * sizeof(unsigned short);
    unsigned short* yh = (unsigned short*)p; p += (size_t)N * D * sizeof(unsigned short);
    unsigned short* Wt = (unsigned short*)p; p += 256 * 128 * sizeof(unsigned short);

    hipMemsetAsync(d_ws, 0, (size_t)N * 3 * sizeof(int), stream);

    k_degrees<<<(E + 255) / 256, 256, 0, stream>>>(src, dst, deg_out, deg_in, E);
    k_norms<<<(N + 255) / 256, 256, 0, stream>>>(deg_out, deg_in, norm_out, norm_in, N);
    k_scan1<<<nscan, 256, 0, stream>>>(deg_in, partial, N);
    k_scan2<<<1, 64, 0, stream>>>(partial, offsets, nscan, N);
    k_scan3<<<nscan, 256, 0, stream>>>(deg_in, partial, offsets, N);
    k_bucket<<<(E + 255) / 256, 256, 0, stream>>>(src, dst, offsets, cursor, edge_src, E);

    long long total4 = (long long)N * D / 4;
    k_x2bf<<<(int)((total4 + 255) / 256), 256, 0, stream>>>(x, xh, total4);
    k_aggr<<<(N + 3) / 4, 256, 0, stream>>>(xh, edge_src, offsets, norm_out, norm_in, yh, N);
    k_wcomb<<<257, 128, 0, stream>>>(Wconv, Waggr, bconv, baggr, Wt, beff);
    k_gemm<<<(N + 63) / 64, 256, 0, stream>>>(yh, xh, Wt, beff, out, N);
}

// Round 4
// 236.401 us; speedup vs baseline: 6.6025x; 1.2385x over previous
//
#include <hip/hip_runtime.h>

#define D 128
#define NB 32              // histogram/scatter blocks per type
#define RBITS 15           // node-range split: 32768 bins per range
#define RSIZE (1 << RBITS)
#define RWORDS (RSIZE / 2) // 16384 packed words = 64 KB LDS

typedef short short8 __attribute__((ext_vector_type(8)));
typedef float f32x4 __attribute__((ext_vector_type(4)));

static __device__ __forceinline__ unsigned short f2bf(float f) {
    unsigned int u = __float_as_uint(f);
    unsigned int r = (u + 0x7FFFu + ((u >> 16) & 1u)) >> 16;
    return (unsigned short)r;
}
static __device__ __forceinline__ float bf2f(unsigned short h) {
    return __uint_as_float(((unsigned int)h) << 16);
}

// ---------------- K1: per-block packed histograms (LDS atomics only) ----------------
// grid (NB, 2 types, RS ranges), block 1024. hist row (type*NB+b) has NW packed words.
__global__ __launch_bounds__(1024) void k_hist(const int* __restrict__ src,
                                               const int* __restrict__ dst,
                                               unsigned int* __restrict__ hist,
                                               int E, int NW) {
    __shared__ unsigned int h[RWORDS];
    int t = threadIdx.x;
    int b = blockIdx.x;
    int type = blockIdx.y;
    int z = blockIdx.z;
    const int* __restrict__ ids = type ? dst : src;
    for (int i = t; i < RWORDS; i += 1024) h[i] = 0;
    __syncthreads();
    int slice = (E + NB - 1) / NB;
    int beg = b * slice;
    int end = beg + slice; if (end > E) end = E;
    for (int e = beg + t; e < end; e += 1024) {
        int v = ids[e];
        if ((v >> RBITS) != z) continue;
        int lv = v & (RSIZE - 1);
        atomicAdd(&h[lv >> 1], 1u << ((lv & 1) * 16));
    }
    __syncthreads();
    unsigned int* out = hist + (size_t)(type * NB + b) * NW;
    int wbeg = z * RWORDS;
    int wend = wbeg + RWORDS; if (wend > NW) wend = NW;
    for (int i = wbeg + t; i < wend; i += 1024) out[i] = h[i - wbeg];
}

// ---------------- K2: reduce hists -> deg_in/norms; rewrite src-hist as dst prefixes ----------------
__global__ __launch_bounds__(256) void k_hreduce(unsigned int* __restrict__ hist,
                                                 int* __restrict__ deg_in,
                                                 float* __restrict__ norm_out,
                                                 float* __restrict__ norm_in,
                                                 int N, int NW) {
    int w = blockIdx.x * blockDim.x + threadIdx.x;
    if (w >= NW) return;
    unsigned int do0 = 0, do1 = 0;
    for (int b = 0; b < NB; b++) {
        unsigned int v = hist[(size_t)b * NW + w];
        do0 += v & 0xffffu; do1 += v >> 16;
    }
    unsigned int p0 = 0, p1 = 0;
    for (int b = 0; b < NB; b++) {
        unsigned int v = hist[(size_t)(NB + b) * NW + w];
        hist[(size_t)b * NW + w] = p0 | (p1 << 16);  // thread-exclusive word: no race
        p0 += v & 0xffffu; p1 += v >> 16;
    }
    int n0 = 2 * w, n1 = 2 * w + 1;
    deg_in[n0]   = (int)p0;
    norm_out[n0] = rsqrtf((float)(do0 > 1 ? do0 : 1));
    norm_in[n0]  = rsqrtf((float)(p0 > 1 ? p0 : 1));
    if (n1 < N) {
        deg_in[n1]   = (int)p1;
        norm_out[n1] = rsqrtf((float)(do1 > 1 ? do1 : 1));
        norm_in[n1]  = rsqrtf((float)(p1 > 1 ? p1 : 1));
    }
}

// ---------------- scan (3-phase): deg_in -> exclusive offsets ----------------
__global__ __launch_bounds__(256) void k_scan1(const int* __restrict__ deg,
                                               int* __restrict__ partial, int N) {
    __shared__ int red[256];
    int t = threadIdx.x;
    int base = blockIdx.x * 1024 + t * 4;
    int s = 0;
    if (base + 3 < N) { int4 v = *(const int4*)&deg[base]; s = v.x + v.y + v.z + v.w; }
    else { for (int i = 0; i < 4; i++) if (base + i < N) s += deg[base + i]; }
    red[t] = s; __syncthreads();
    for (int off = 128; off > 0; off >>= 1) {
        if (t < off) red[t] += red[t + off];
        __syncthreads();
    }
    if (t == 0) partial[blockIdx.x] = red[0];
}

__global__ void k_scan2(int* __restrict__ partial, int* __restrict__ offsets, int nb, int N) {
    if (threadIdx.x == 0) {
        int run = 0;
        for (int i = 0; i < nb; i++) { int v = partial[i]; partial[i] = run; run += v; }
        offsets[N] = run;
    }
}

__global__ __launch_bounds__(256) void k_scan3(const int* __restrict__ deg,
                                               const int* __restrict__ partial,
                                               int* __restrict__ offsets, int N) {
    __shared__ int red[256];
    int t = threadIdx.x;
    int base = blockIdx.x * 1024 + t * 4;
    int v[4]; int s = 0;
    for (int i = 0; i < 4; i++) { v[i] = (base + i < N) ? deg[base + i] : 0; s += v[i]; }
    red[t] = s; __syncthreads();
    for (int off = 1; off < 256; off <<= 1) {
        int a = (t >= off) ? red[t - off] : 0;
        __syncthreads();
        red[t] += a;
        __syncthreads();
    }
    int excl = red[t] - s + partial[blockIdx.x];
    for (int i = 0; i < 4; i++) { if (base + i < N) offsets[base + i] = excl; excl += v[i]; }
}

// ---------------- K4: counting-sort scatter — no global atomics ----------------
// grid (NB, RS ranges), block 1024. Same edge slicing as k_hist.
__global__ __launch_bounds__(1024) void k_scatter(const int* __restrict__ src,
                                                  const int* __restrict__ dst,
                                                  const int* __restrict__ offsets,
                                                  const unsigned int* __restrict__ prefix,
                                                  int* __restrict__ edge_src,
                                                  int E, int NW) {
    __shared__ unsigned int h[RWORDS];
    int t = threadIdx.x;
    int b = blockIdx.x;
    int z = blockIdx.y;
    for (int i = t; i < RWORDS; i += 1024) h[i] = 0;
    __syncthreads();
    int slice = (E + NB - 1) / NB;
    int beg = b * slice;
    int end = beg + slice; if (end > E) end = E;
    const unsigned int* __restrict__ prow = prefix + (size_t)b * NW;
    for (int e = beg + t; e < end; e += 1024) {
        int d = dst[e];
        if ((d >> RBITS) != z) continue;
        int lv = d & (RSIZE - 1);
        int sh = (lv & 1) * 16;
        unsigned int old = atomicAdd(&h[lv >> 1], 1u << sh);
        int rank = (int)((old >> sh) & 0xffffu);
        int base = offsets[d] + (int)((prow[d >> 1] >> sh) & 0xffffu);
        edge_src[base + rank] = src[e];
    }
}

// ---------------- x -> bf16 ----------------
__global__ __launch_bounds__(256) void k_x2bf(const float* __restrict__ x,
                                              unsigned short* __restrict__ xh, long long total4) {
    long long i = (long long)blockIdx.x * blockDim.x + threadIdx.x;
    if (i < total4) {
        float4 v = *(const float4*)&x[i * 4];
        ushort4 o;
        o.x = f2bf(v.x); o.y = f2bf(v.y); o.z = f2bf(v.z); o.w = f2bf(v.w);
        *(ushort4*)&xh[i * 4] = o;
    }
}

// ---------------- CSR aggregation ----------------
__global__ __launch_bounds__(256) void k_aggr(const unsigned short* __restrict__ xh,
                                              const int* __restrict__ edge_src,
                                              const int* __restrict__ offsets,
                                              const float* __restrict__ norm_out,
                                              const float* __restrict__ norm_in,
                                              unsigned short* __restrict__ yh, int N) {
    int node = blockIdx.x * 4 + (threadIdx.x >> 6);
    int lane = threadIdx.x & 63;
    if (node >= N) return;
    int beg = offsets[node];
    int end = offsets[node + 1];
    float ax = 0.f, ay = 0.f;
#pragma unroll 2
    for (int j = beg; j < end; j++) {
        int s = edge_src[j];
        float ns = norm_out[s];
        ushort2 v = *(const ushort2*)&xh[(size_t)s * D + lane * 2];
        ax += bf2f(v.x) * ns;
        ay += bf2f(v.y) * ns;
    }
    float nd = norm_in[node];
    ushort2 o;
    o.x = f2bf(ax * nd);
    o.y = f2bf(ay * nd);
    *(ushort2*)&yh[(size_t)node * D + lane * 2] = o;
}

// ---------------- fold W_conv into W_aggr; bf16 transposed Wt[n][k] ----------------
__global__ void k_wcomb(const float* __restrict__ Wc, const float* __restrict__ Wa,
                        const float* __restrict__ bc, const float* __restrict__ ba,
                        unsigned short* __restrict__ Wt, float* __restrict__ beff) {
    int b = blockIdx.x;   // k index 0..255, or 256 for bias
    int j = threadIdx.x;  // n index, 128 threads
    if (b < 128) {
        float acc = 0.f;
        for (int k = 0; k < 128; k++) acc += Wc[b * 128 + k] * Wa[k * 128 + j];
        Wt[(size_t)j * 256 + b] = f2bf(acc);
    } else if (b < 256) {
        Wt[(size_t)j * 256 + b] = f2bf(Wa[b * 128 + j]);
    } else {
        float acc = ba[j];
        for (int k = 0; k < 128; k++) acc += bc[k] * Wa[k * 128 + j];
        beff[j] = acc;
    }
}

// ---------------- MFMA GEMM: out = [yh | xh] @ W + beff ----------------
#define WT_STRIDE 136
__global__ __launch_bounds__(256) void k_gemm(const unsigned short* __restrict__ yh,
                                              const unsigned short* __restrict__ xh,
                                              const unsigned short* __restrict__ Wt,
                                              const float* __restrict__ beff,
                                              float* __restrict__ out, int N) {
    __shared__ unsigned short Bs[128 * WT_STRIDE];

    int t = threadIdx.x;
    int w = t >> 6;
    int lane = t & 63;
    int m = lane & 15;
    int q = lane >> 4;
    int row0 = blockIdx.x * 64;
    int arow = row0 + w * 16 + m;
    bool arow_ok = arow < N;

    f32x4 acc[8];
#pragma unroll
    for (int ct = 0; ct < 8; ct++) acc[ct] = (f32x4){0.f, 0.f, 0.f, 0.f};

    for (int kh = 0; kh < 2; kh++) {
#pragma unroll
        for (int i = 0; i < 8; i++) {
            int idx = t + i * 256;
            int rr = idx >> 4;
            int cc = (idx & 15) * 8;
            *(short8*)&Bs[rr * WT_STRIDE + cc] =
                *(const short8*)&Wt[(size_t)rr * 256 + kh * 128 + cc];
        }
        __syncthreads();

        const unsigned short* Abase = (kh == 0) ? yh : xh;
        const unsigned short* arowp = Abase + (size_t)arow * D;

#pragma unroll
        for (int kk = 0; kk < 4; kk++) {
            short8 a = (short8){0,0,0,0,0,0,0,0};
            if (arow_ok) a = *(const short8*)&arowp[kk * 32 + q * 8];
#pragma unroll
            for (int ct = 0; ct < 8; ct++) {
                short8 b = *(const short8*)&Bs[(ct * 16 + m) * WT_STRIDE + kk * 32 + q * 8];
                acc[ct] = __builtin_amdgcn_mfma_f32_16x16x32_bf16(a, b, acc[ct], 0, 0, 0);
            }
        }
        __syncthreads();
    }

#pragma unroll
    for (int ct = 0; ct < 8; ct++) {
        int col = ct * 16 + m;
        float bv = beff[col];
#pragma unroll
        for (int j = 0; j < 4; j++) {
            int r = row0 + w * 16 + q * 4 + j;
            if (r < N) out[(size_t)r * D + col] = acc[ct][j] + bv;
        }
    }
}

static size_t align256(size_t v) { return (v + 255) & ~(size_t)255; }

extern "C" void kernel_launch(void* const* d_in, const int* in_sizes, int n_in,
                              void* d_out, int out_size, void* d_ws, size_t ws_size,
                              hipStream_t stream) {
    const float* x     = (const float*)d_in[0];
    const int*   src   = (const int*)d_in[1];
    const int*   dst   = (const int*)d_in[2];
    const float* Wconv = (const float*)d_in[3];
    const float* bconv = (const float*)d_in[4];
    const float* Waggr = (const float*)d_in[5];
    const float* baggr = (const float*)d_in[6];
    float* out = (float*)d_out;

    int N = in_sizes[0] / D;
    int E = in_sizes[1];
    int NW = (N + 1) / 2;               // packed words per histogram row
    int RS = (N + RSIZE - 1) / RSIZE;   // node-range splits
    int nscan = (N + 1023) / 1024;

    char* p = (char*)d_ws;
    // hist: [src half: NB rows][dst half: NB rows]; after k_hreduce the src half
    // holds per-block dst prefixes and the dst half is dead -> edge_src overlays it.
    unsigned int* hist = (unsigned int*)p;
    int* edge_src = (int*)(hist + (size_t)NB * NW);
    size_t dstHalf = (size_t)NB * NW * 4;
    size_t edgeBytes = (size_t)E * 4;
    p += align256((size_t)NB * NW * 4 + (edgeBytes > dstHalf ? edgeBytes : dstHalf));
    int* deg_in  = (int*)p;      p += align256((size_t)N * sizeof(int));
    int* offsets = (int*)p;      p += align256((size_t)(N + 1) * sizeof(int));
    int* partial = (int*)p;      p += align256((size_t)(nscan + 1) * sizeof(int));
    float* norm_out = (float*)p; p += align256((size_t)N * sizeof(float));
    float* norm_in  = (float*)p; p += align256((size_t)N * sizeof(float));
    float* beff  = (float*)p;    p += align256(128 * sizeof(float));
    unsigned short* xh = (unsigned short*)p; p += align256((size_t)N * D * 2);
    unsigned short* yh = (unsigned short*)p; p += align256((size_t)N * D * 2);
    unsigned short* Wt = (unsigned short*)p; p += align256(256 * 128 * 2);

    k_hist<<<dim3(NB, 2, RS), 1024, 0, stream>>>(src, dst, hist, E, NW);
    k_hreduce<<<(NW + 255) / 256, 256, 0, stream>>>(hist, deg_in, norm_out, norm_in, N, NW);
    k_scan1<<<nscan, 256, 0, stream>>>(deg_in, partial, N);
    k_scan2<<<1, 64, 0, stream>>>(partial, offsets, nscan, N);
    k_scan3<<<nscan, 256, 0, stream>>>(deg_in, partial, offsets, N);
    k_scatter<<<dim3(NB, RS), 1024, 0, stream>>>(src, dst, offsets, hist, edge_src, E, NW);

    long long total4 = (long long)N * D / 4;
    k_x2bf<<<(int)((total4 + 255) / 256), 256, 0, stream>>>(x, xh, total4);
    k_aggr<<<(N + 3) / 4, 256, 0, stream>>>(xh, edge_src, offsets, norm_out, norm_in, yh, N);
    k_wcomb<<<257, 128, 0, stream>>>(Wconv, Waggr, bconv, baggr, Wt, beff);
    k_gemm<<<(N + 63) / 64, 256, 0, stream>>>(yh, xh, Wt, beff, out, N);
}

// Round 5
// 217.515 us; speedup vs baseline: 7.1758x; 1.0868x over previous
//
#include <hip/hip_runtime.h>

#define D 128
#define NB 32              // histogram/scatter blocks per type
#define RBITS 15           // node-range split: 32768 bins per range
#define RSIZE (1 << RBITS)
#define RWORDS (RSIZE / 2) // 16384 packed words = 64 KB LDS

typedef short short8 __attribute__((ext_vector_type(8)));
typedef float f32x4 __attribute__((ext_vector_type(4)));

static __device__ __forceinline__ unsigned short f2bf(float f) {
    unsigned int u = __float_as_uint(f);
    unsigned int r = (u + 0x7FFFu + ((u >> 16) & 1u)) >> 16;
    return (unsigned short)r;
}
static __device__ __forceinline__ unsigned int pk2bf(float lo, float hi) {
    return (unsigned int)f2bf(lo) | ((unsigned int)f2bf(hi) << 16);
}

// ---------------- K1: per-block packed histograms (LDS atomics only) ----------------
__global__ __launch_bounds__(1024) void k_hist(const int* __restrict__ src,
                                               const int* __restrict__ dst,
                                               unsigned int* __restrict__ hist,
                                               int E, int NW) {
    __shared__ unsigned int h[RWORDS];
    int t = threadIdx.x;
    int b = blockIdx.x;
    int type = blockIdx.y;
    int z = blockIdx.z;
    const int* __restrict__ ids = type ? dst : src;
    for (int i = t; i < RWORDS; i += 1024) h[i] = 0;
    __syncthreads();
    int slice = (E + NB - 1) / NB;
    int beg = b * slice;
    int end = beg + slice; if (end > E) end = E;
    for (int e = beg + t; e < end; e += 1024) {
        int v = ids[e];
        if ((v >> RBITS) != z) continue;
        int lv = v & (RSIZE - 1);
        atomicAdd(&h[lv >> 1], 1u << ((lv & 1) * 16));
    }
    __syncthreads();
    unsigned int* out = hist + (size_t)(type * NB + b) * NW;
    int wbeg = z * RWORDS;
    int wend = wbeg + RWORDS; if (wend > NW) wend = NW;
    for (int i = wbeg + t; i < wend; i += 1024) out[i] = h[i - wbeg];
}

// ---------------- K2: reduce hists -> deg/norms; rewrite src-hist as dst prefixes;
//                     also emit per-block partial sums (fused scan phase 1) ----------------
__global__ __launch_bounds__(256) void k_hreduce(unsigned int* __restrict__ hist,
                                                 int* __restrict__ deg_in,
                                                 float* __restrict__ norm_out,
                                                 float* __restrict__ norm_in,
                                                 int* __restrict__ partial,
                                                 int N, int NW) {
    __shared__ int red[256];
    int t = threadIdx.x;
    int w = blockIdx.x * 256 + t;
    unsigned int p0 = 0, p1 = 0;
    if (w < NW) {
        unsigned int do0 = 0, do1 = 0;
        for (int b = 0; b < NB; b++) {
            unsigned int v = hist[(size_t)b * NW + w];
            do0 += v & 0xffffu; do1 += v >> 16;
        }
        for (int b = 0; b < NB; b++) {
            unsigned int v = hist[(size_t)(NB + b) * NW + w];
            hist[(size_t)b * NW + w] = p0 | (p1 << 16);  // thread-exclusive word: no race
            p0 += v & 0xffffu; p1 += v >> 16;
        }
        int n0 = 2 * w, n1 = 2 * w + 1;
        deg_in[n0]   = (int)p0;
        norm_out[n0] = rsqrtf((float)(do0 > 1 ? do0 : 1));
        norm_in[n0]  = rsqrtf((float)(p0 > 1 ? p0 : 1));
        if (n1 < N) {
            deg_in[n1]   = (int)p1;
            norm_out[n1] = rsqrtf((float)(do1 > 1 ? do1 : 1));
            norm_in[n1]  = rsqrtf((float)(p1 > 1 ? p1 : 1));
        } else {
            p1 = 0;
        }
    }
    red[t] = (int)(p0 + p1);
    __syncthreads();
    for (int off = 128; off > 0; off >>= 1) {
        if (t < off) red[t] += red[t + off];
        __syncthreads();
    }
    if (t == 0) partial[blockIdx.x] = red[0];
}

__global__ void k_scan2(int* __restrict__ partial, int* __restrict__ offsets, int nb, int N) {
    if (threadIdx.x == 0) {
        int run = 0;
        for (int i = 0; i < nb; i++) { int v = partial[i]; partial[i] = run; run += v; }
        offsets[N] = run;
    }
}

// 512 nodes per block (matches k_hreduce partition)
__global__ __launch_bounds__(256) void k_scan3(const int* __restrict__ deg,
                                               const int* __restrict__ partial,
                                               int* __restrict__ offsets, int N) {
    __shared__ int red[256];
    int t = threadIdx.x;
    int base = blockIdx.x * 512 + t * 2;
    int v0 = (base < N) ? deg[base] : 0;
    int v1 = (base + 1 < N) ? deg[base + 1] : 0;
    int s = v0 + v1;
    red[t] = s;
    __syncthreads();
    for (int off = 1; off < 256; off <<= 1) {
        int a = (t >= off) ? red[t - off] : 0;
        __syncthreads();
        red[t] += a;
        __syncthreads();
    }
    int excl = red[t] - s + partial[blockIdx.x];
    if (base < N)     offsets[base] = excl;
    if (base + 1 < N) offsets[base + 1] = excl + v0;
}

// ---------------- K4: counting-sort scatter — no global atomics ----------------
__global__ __launch_bounds__(1024) void k_scatter(const int* __restrict__ src,
                                                  const int* __restrict__ dst,
                                                  const int* __restrict__ offsets,
                                                  const unsigned int* __restrict__ prefix,
                                                  int* __restrict__ edge_src,
                                                  int E, int NW) {
    __shared__ unsigned int h[RWORDS];
    int t = threadIdx.x;
    int b = blockIdx.x;
    int z = blockIdx.y;
    for (int i = t; i < RWORDS; i += 1024) h[i] = 0;
    __syncthreads();
    int slice = (E + NB - 1) / NB;
    int beg = b * slice;
    int end = beg + slice; if (end > E) end = E;
    const unsigned int* __restrict__ prow = prefix + (size_t)b * NW;
    for (int e = beg + t; e < end; e += 1024) {
        int d = dst[e];
        if ((d >> RBITS) != z) continue;
        int lv = d & (RSIZE - 1);
        int sh = (lv & 1) * 16;
        unsigned int old = atomicAdd(&h[lv >> 1], 1u << sh);
        int rank = (int)((old >> sh) & 0xffffu);
        int base = offsets[d] + (int)((prow[d >> 1] >> sh) & 0xffffu);
        edge_src[base + rank] = src[e];
    }
}

// ---------------- x -> bf16 (xh) and bf16 pre-scaled by norm_out (xsh) ----------------
__global__ __launch_bounds__(256) void k_x2bf(const float* __restrict__ x,
                                              const float* __restrict__ norm_out,
                                              unsigned short* __restrict__ xh,
                                              unsigned short* __restrict__ xsh,
                                              long long total4) {
    long long i = (long long)blockIdx.x * blockDim.x + threadIdx.x;
    if (i >= total4) return;
    int row = (int)(i >> 5);   // 32 float4 per 128-wide row
    float ns = norm_out[row];
    float4 v = *(const float4*)&x[i * 4];
    ushort4 o;
    o.x = f2bf(v.x); o.y = f2bf(v.y); o.z = f2bf(v.z); o.w = f2bf(v.w);
    *(ushort4*)&xh[i * 4] = o;
    ushort4 os;
    os.x = f2bf(v.x * ns); os.y = f2bf(v.y * ns); os.z = f2bf(v.z * ns); os.w = f2bf(v.w * ns);
    *(ushort4*)&xsh[i * 4] = os;
}

// ---------------- CSR aggregation: 4 rows in flight per wave ----------------
// wave = 4 groups x 16 lanes; group g gathers edge (k+g)'s row, 16B/lane.
__global__ __launch_bounds__(256) void k_aggr(const unsigned short* __restrict__ xsh,
                                              const int* __restrict__ edge_src,
                                              const int* __restrict__ offsets,
                                              const float* __restrict__ norm_in,
                                              unsigned short* __restrict__ yh, int N) {
    int node = blockIdx.x * 4 + (threadIdx.x >> 6);
    int lane = threadIdx.x & 63;
    if (node >= N) return;
    int g = lane >> 4;
    int li = lane & 15;
    int beg = offsets[node];
    int end = offsets[node + 1];

    float acc[8];
#pragma unroll
    for (int i = 0; i < 8; i++) acc[i] = 0.f;

    for (int jb = beg; jb < end; jb += 64) {
        int cnt = end - jb; if (cnt > 64) cnt = 64;
        int eidx = (lane < cnt) ? edge_src[jb + lane] : 0;  // coalesced batch
#pragma unroll 4
        for (int k = 0; k < cnt; k += 4) {
            int kg = k + g;
            int s = __shfl(eidx, kg);
            if (kg < cnt) {
                uint4 raw = *(const uint4*)&xsh[(size_t)s * D + li * 8];
                acc[0] += __uint_as_float(raw.x << 16);
                acc[1] += __uint_as_float(raw.x & 0xffff0000u);
                acc[2] += __uint_as_float(raw.y << 16);
                acc[3] += __uint_as_float(raw.y & 0xffff0000u);
                acc[4] += __uint_as_float(raw.z << 16);
                acc[5] += __uint_as_float(raw.z & 0xffff0000u);
                acc[6] += __uint_as_float(raw.w << 16);
                acc[7] += __uint_as_float(raw.w & 0xffff0000u);
            }
        }
    }

    // combine the 4 groups (butterfly over lane bits 4,5)
#pragma unroll
    for (int i = 0; i < 8; i++) {
        acc[i] += __shfl_xor(acc[i], 16);
        acc[i] += __shfl_xor(acc[i], 32);
    }

    if (g == 0) {
        float nd = norm_in[node];
        uint4 o;
        o.x = pk2bf(acc[0] * nd, acc[1] * nd);
        o.y = pk2bf(acc[2] * nd, acc[3] * nd);
        o.z = pk2bf(acc[4] * nd, acc[5] * nd);
        o.w = pk2bf(acc[6] * nd, acc[7] * nd);
        *(uint4*)&yh[(size_t)node * D + li * 8] = o;
    }
}

// ---------------- fold W_conv into W_aggr; bf16 transposed Wt[n][k] ----------------
__global__ void k_wcomb(const float* __restrict__ Wc, const float* __restrict__ Wa,
                        const float* __restrict__ bc, const float* __restrict__ ba,
                        unsigned short* __restrict__ Wt, float* __restrict__ beff) {
    int b = blockIdx.x;   // k index 0..255, or 256 for bias
    int j = threadIdx.x;  // n index, 128 threads
    if (b < 128) {
        float acc = 0.f;
        for (int k = 0; k < 128; k++) acc += Wc[b * 128 + k] * Wa[k * 128 + j];
        Wt[(size_t)j * 256 + b] = f2bf(acc);
    } else if (b < 256) {
        Wt[(size_t)j * 256 + b] = f2bf(Wa[b * 128 + j]);
    } else {
        float acc = ba[j];
        for (int k = 0; k < 128; k++) acc += bc[k] * Wa[k * 128 + j];
        beff[j] = acc;
    }
}

// ---------------- MFMA GEMM: out = [yh | xh] @ W + beff ----------------
#define WT_STRIDE 136
__global__ __launch_bounds__(256) void k_gemm(const unsigned short* __restrict__ yh,
                                              const unsigned short* __restrict__ xh,
                                              const unsigned short* __restrict__ Wt,
                                              const float* __restrict__ beff,
                                              float* __restrict__ out, int N) {
    __shared__ unsigned short Bs[128 * WT_STRIDE];

    int t = threadIdx.x;
    int w = t >> 6;
    int lane = t & 63;
    int m = lane & 15;
    int q = lane >> 4;
    int row0 = blockIdx.x * 64;
    int arow = row0 + w * 16 + m;
    bool arow_ok = arow < N;

    f32x4 acc[8];
#pragma unroll
    for (int ct = 0; ct < 8; ct++) acc[ct] = (f32x4){0.f, 0.f, 0.f, 0.f};

    for (int kh = 0; kh < 2; kh++) {
#pragma unroll
        for (int i = 0; i < 8; i++) {
            int idx = t + i * 256;
            int rr = idx >> 4;
            int cc = (idx & 15) * 8;
            *(short8*)&Bs[rr * WT_STRIDE + cc] =
                *(const short8*)&Wt[(size_t)rr * 256 + kh * 128 + cc];
        }
        __syncthreads();

        const unsigned short* Abase = (kh == 0) ? yh : xh;
        const unsigned short* arowp = Abase + (size_t)arow * D;

#pragma unroll
        for (int kk = 0; kk < 4; kk++) {
            short8 a = (short8){0,0,0,0,0,0,0,0};
            if (arow_ok) a = *(const short8*)&arowp[kk * 32 + q * 8];
#pragma unroll
            for (int ct = 0; ct < 8; ct++) {
                short8 b = *(const short8*)&Bs[(ct * 16 + m) * WT_STRIDE + kk * 32 + q * 8];
                acc[ct] = __builtin_amdgcn_mfma_f32_16x16x32_bf16(a, b, acc[ct], 0, 0, 0);
            }
        }
        __syncthreads();
    }

#pragma unroll
    for (int ct = 0; ct < 8; ct++) {
        int col = ct * 16 + m;
        float bv = beff[col];
#pragma unroll
        for (int j = 0; j < 4; j++) {
            int r = row0 + w * 16 + q * 4 + j;
            if (r < N) out[(size_t)r * D + col] = acc[ct][j] + bv;
        }
    }
}

static size_t align256(size_t v) { return (v + 255) & ~(size_t)255; }

extern "C" void kernel_launch(void* const* d_in, const int* in_sizes, int n_in,
                              void* d_out, int out_size, void* d_ws, size_t ws_size,
                              hipStream_t stream) {
    const float* x     = (const float*)d_in[0];
    const int*   src   = (const int*)d_in[1];
    const int*   dst   = (const int*)d_in[2];
    const float* Wconv = (const float*)d_in[3];
    const float* bconv = (const float*)d_in[4];
    const float* Waggr = (const float*)d_in[5];
    const float* baggr = (const float*)d_in[6];
    float* out = (float*)d_out;

    int N = in_sizes[0] / D;
    int E = in_sizes[1];
    int NW = (N + 1) / 2;               // packed words per histogram row
    int RS = (N + RSIZE - 1) / RSIZE;   // node-range splits
    int nbh = (NW + 255) / 256;         // hreduce/scan blocks (512 nodes each)

    char* p = (char*)d_ws;
    // hist: [src half: NB rows][dst half: NB rows]; after k_hreduce the src half
    // holds per-block dst prefixes and the dst half is dead -> edge_src overlays it.
    unsigned int* hist = (unsigned int*)p;
    int* edge_src = (int*)(hist + (size_t)NB * NW);
    size_t dstHalf = (size_t)NB * NW * 4;
    size_t edgeBytes = (size_t)E * 4;
    p += align256((size_t)NB * NW * 4 + (edgeBytes > dstHalf ? edgeBytes : dstHalf));
    int* deg_in  = (int*)p;      p += align256((size_t)N * sizeof(int));
    int* offsets = (int*)p;      p += align256((size_t)(N + 1) * sizeof(int));
    int* partial = (int*)p;      p += align256((size_t)(nbh + 1) * sizeof(int));
    float* norm_out = (float*)p; p += align256((size_t)N * sizeof(float));
    float* norm_in  = (float*)p; p += align256((size_t)N * sizeof(float));
    float* beff  = (float*)p;    p += align256(128 * sizeof(float));
    unsigned short* xh  = (unsigned short*)p; p += align256((size_t)N * D * 2);
    unsigned short* xsh = (unsigned short*)p; p += align256((size_t)N * D * 2);
    unsigned short* yh  = (unsigned short*)p; p += align256((size_t)N * D * 2);
    unsigned short* Wt  = (unsigned short*)p; p += align256(256 * 128 * 2);

    k_hist<<<dim3(NB, 2, RS), 1024, 0, stream>>>(src, dst, hist, E, NW);
    k_hreduce<<<nbh, 256, 0, stream>>>(hist, deg_in, norm_out, norm_in, partial, N, NW);
    k_scan2<<<1, 64, 0, stream>>>(partial, offsets, nbh, N);
    k_scan3<<<nbh, 256, 0, stream>>>(deg_in, partial, offsets, N);
    k_scatter<<<dim3(NB, RS), 1024, 0, stream>>>(src, dst, offsets, hist, edge_src, E, NW);

    long long total4 = (long long)N * D / 4;
    k_x2bf<<<(int)((total4 + 255) / 256), 256, 0, stream>>>(x, norm_out, xh, xsh, total4);
    k_aggr<<<(N + 3) / 4, 256, 0, stream>>>(xsh, edge_src, offsets, norm_in, yh, N);
    k_wcomb<<<257, 128, 0, stream>>>(Wconv, Waggr, bconv, baggr, Wt, beff);
    k_gemm<<<(N + 63) / 64, 256, 0, stream>>>(yh, xh, Wt, beff, out, N);
}